// Round 5
// baseline (108.077 us; speedup 1.0000x reference)
//
#include <hip/hip_runtime.h>
#include <math.h>
#include <limits.h>

// out[b,h,w,c] = vgg[b,h,w,c] - t[b,h,w]
//   t = (a > 0.5f) ? a : 0,  a[b,h,w] = interm[b,h,w, argmax_c logits[b,c]]
// B=256, H=W=7 (P=49 positions), C_in=1000, C_out=512. All fp32.
//
// Fused kernel, register-preload variant.
// Evidence so far: fills sustain 81% HBM peak at 8.3% occupancy -> occupancy
// is not the lever (r0 KBLK=4 == r4 KBLK=8 confirmed). Remaining slack is the
// serial argmax->gather latency prefix (2-3 dependent HBM round-trips) during
// which no streaming bytes move, synchronized across ALL blocks at launch.
// Fix: issue each thread's 3-4 vgg float4 loads FIRST (addresses are
// argmax-independent), so they fly during the logits load + reduce; the
// compiler's vmcnt(0) drain at the first __syncthreads completes them "for
// free". Epilogue is register-resident subtract + store.

#define NB     256      // batch
#define NP     49       // 7*7 positions
#define CIN    1000     // interm / logits channels
#define COUT   512      // vgg channels
#define VEC_PER_SAMPLE (NP * COUT / 4)   // 6272 float4 per sample
#define KBLK   8        // blocks per sample -> 2048 blocks total
#define STRIDE (KBLK * 256)              // 2048 float4 per block-row

__global__ __launch_bounds__(256) void cam_sub_fused(
    const float* __restrict__ vgg,
    const float* __restrict__ interm,
    const float* __restrict__ logits,
    float* __restrict__ out)
{
    const int b     = blockIdx.x >> 3;        // KBLK = 8
    const int chunk = blockIdx.x & (KBLK - 1);
    const int tid   = threadIdx.x;

    // ---- issue streaming reads FIRST (independent of argmax) ----
    // v0 in [0,2048): v0, v0+2048, v0+4096 always < 6272; v0+6144 iff v0 < 128.
    const int v0 = chunk * 256 + tid;
    const float4* __restrict__ vgg4 = (const float4*)(vgg + (size_t)b * NP * COUT);
    float4*       __restrict__ out4 = (float4*)(out + (size_t)b * NP * COUT);
    const bool tail = v0 < (VEC_PER_SAMPLE - 3 * STRIDE);   // v0 < 128
    float4 x0 = vgg4[v0];
    float4 x1 = vgg4[v0 + STRIDE];
    float4 x2 = vgg4[v0 + 2 * STRIDE];
    float4 x3;
    if (tail) x3 = vgg4[v0 + 3 * STRIDE];

    // ---- per-sample argmax over logits[b, 0..999] (first-index tie-break,
    //      matching jnp.argmax). 1000 = 250 float4: one vector load/thread. ----
    const float4* __restrict__ lg4 = (const float4*)(logits + b * CIN);
    float bv = -INFINITY;
    int   bi = INT_MAX;
    if (tid < CIN / 4) {
        float4 v = lg4[tid];
        bv = v.x; bi = 4 * tid;
        if (v.y > bv) { bv = v.y; bi = 4 * tid + 1; }   // strictly-greater keeps
        if (v.z > bv) { bv = v.z; bi = 4 * tid + 2; }   // first index within the 4
        if (v.w > bv) { bv = v.w; bi = 4 * tid + 3; }
    }
    // wave-64 butterfly-down reduce with first-index tie-break
    for (int off = 32; off >= 1; off >>= 1) {
        float ov = __shfl_down(bv, off, 64);
        int   oi = __shfl_down(bi, off, 64);
        if (ov > bv || (ov == bv && oi < bi)) { bv = ov; bi = oi; }
    }
    __shared__ float wv[4];
    __shared__ int   wi[4];
    __shared__ int   s_idx;
    __shared__ float s_a[NP];
    const int wave = tid >> 6;
    if ((tid & 63) == 0) { wv[wave] = bv; wi[wave] = bi; }
    __syncthreads();                 // also drains the in-flight vgg loads
    if (tid == 0) {
        float v = wv[0]; int i = wi[0];
        #pragma unroll
        for (int w = 1; w < 4; ++w)
            if (wv[w] > v || (wv[w] == v && wi[w] < i)) { v = wv[w]; i = wi[w]; }
        s_idx = i;
    }
    __syncthreads();
    const int idx = s_idx;

    // ---- gather + threshold the 49 CAM values into LDS ----
    if (tid < NP) {
        float a = interm[((size_t)b * NP + tid) * CIN + idx];
        s_a[tid] = (a > 0.5f) ? a : 0.0f;
    }
    __syncthreads();

    // ---- register-resident subtract + store ----
    {
        const float a0 = s_a[v0 >> 7];                 // 128 float4 per position
        const float a1 = s_a[(v0 + STRIDE) >> 7];
        const float a2 = s_a[(v0 + 2 * STRIDE) >> 7];
        x0.x -= a0; x0.y -= a0; x0.z -= a0; x0.w -= a0;
        x1.x -= a1; x1.y -= a1; x1.z -= a1; x1.w -= a1;
        x2.x -= a2; x2.y -= a2; x2.z -= a2; x2.w -= a2;
        out4[v0]              = x0;
        out4[v0 + STRIDE]     = x1;
        out4[v0 + 2 * STRIDE] = x2;
        if (tail) {
            const float a3 = s_a[(v0 + 3 * STRIDE) >> 7];
            x3.x -= a3; x3.y -= a3; x3.z -= a3; x3.w -= a3;
            out4[v0 + 3 * STRIDE] = x3;
        }
    }
}

extern "C" void kernel_launch(void* const* d_in, const int* in_sizes, int n_in,
                              void* d_out, int out_size, void* d_ws, size_t ws_size,
                              hipStream_t stream) {
    const float* vgg    = (const float*)d_in[0];  // [256,7,7,512]
    const float* interm = (const float*)d_in[1];  // [256,7,7,1000]
    const float* logits = (const float*)d_in[2];  // [256,1000]
    float* out = (float*)d_out;                   // [256,7,7,512]

    hipLaunchKernelGGL(cam_sub_fused, dim3(NB * KBLK), dim3(256), 0, stream,
                       vgg, interm, logits, out);
}